// Round 5
// baseline (292.750 us; speedup 1.0000x reference)
//
#include <hip/hip_runtime.h>
#include <hip/hip_bf16.h>

// Problem constants
#define Bsz 8192
#define Isz 1024
#define Hsz 1024
#define Ksz 2048   // I + H (concatenated GEMM K)
#define Nsz 4096   // 4*H  (stacked gates)

// GEMM tiling: 256x256 tile, BK=64, 8 waves (2M x 4N)
#define BM 256
#define BN 256
#define BK 64
#define NT (Ksz / BK)      // 32 K-tiles
#define BUF (BM * BK)      // 16384 bf16 elems = 32 KB per buffer

typedef __attribute__((ext_vector_type(8))) short bf16x8;  // 8 bf16 = 4 VGPRs
typedef __attribute__((ext_vector_type(4))) float f32x4;
typedef __attribute__((ext_vector_type(8))) unsigned short ushort8;

__device__ __forceinline__ void async_copy16(const void* g, void* l) {
  __builtin_amdgcn_global_load_lds(
      (const __attribute__((address_space(1))) void*)g,
      (__attribute__((address_space(3))) void*)l, 16, 0, 0);
}

__device__ __forceinline__ float fast_rcp(float x) {
  return __builtin_amdgcn_rcpf(x);   // v_rcp_f32, ~1ulp; tolerance is 3e-2
}
__device__ __forceinline__ float sigmoid_f(float x) {
  return fast_rcp(1.0f + __expf(-x));
}
__device__ __forceinline__ float tanh_f(float x) {
  x = fminf(15.0f, fmaxf(-15.0f, x));   // avoid inf/inf -> NaN
  const float e = __expf(-2.0f * x);
  return (1.0f - e) * fast_rcp(1.0f + e);
}

// register-only f32 -> bf16 bits (no local-array puns -> no scratch)
__device__ __forceinline__ unsigned short bfc(float f) {
  return __builtin_bit_cast(unsigned short, __float2bfloat16(f));
}
__device__ __forceinline__ ushort8 cvt8v(float4 v0, float4 v1) {
  ushort8 o;
  o[0] = bfc(v0.x); o[1] = bfc(v0.y); o[2] = bfc(v0.z); o[3] = bfc(v0.w);
  o[4] = bfc(v1.x); o[5] = bfc(v1.y); o[6] = bfc(v1.z); o[7] = bfc(v1.w);
  return o;
}

// ---------------------------------------------------------------------------
// Prep v2: build bf16 A=[x|h] (8192x2048), gate-interleaved bf16 W'
// (4096x2048), bsum[4*hh+g]=bx+bh.
//
// ROUND-5 EXPERIMENT: the total-minus-GEMM residue has been ~143-158 us in
// every bench; prep's compulsory traffic is 144 MB (~23 us at 6.3 TB/s), so
// either prep runs at ~1.1 TB/s or the residue is harness floor. This
// rewrite applies Guideline 11 for memory-bound kernels: grid = 2048 blocks
// (8/CU, full occupancy), 3 fat iterations per thread, 64 B of independent
// float4 loads per iteration (ILP for latency hiding), 2x ushort8 stores.
// Indexing math and output layout identical to v1. Waves never straddle the
// x/h (or Wx/Wh) boundary: 64 consecutive 16-elem segments span exactly one
// half of a 2048-elem row -> no divergence.
// ---------------------------------------------------------------------------
__global__ __launch_bounds__(256) void prep_kernel(
    const float* __restrict__ x, const float* __restrict__ h,
    const float* __restrict__ Wx, const float* __restrict__ Wh,
    const float* __restrict__ bx, const float* __restrict__ bh,
    __hip_bfloat16* __restrict__ Abf, __hip_bfloat16* __restrict__ Wbf,
    float* __restrict__ bsum) {
  const int idx = blockIdx.x * 256 + threadIdx.x;   // 524,288 threads

  // A: 8192 rows x 128 segments of 16 elems = 1,048,576 segs; 2 per thread
#pragma unroll
  for (int rep = 0; rep < 2; ++rep) {
    const int p = idx + rep * (1 << 19);
    const int b = p >> 7;              // row
    const int kk = (p & 127) << 4;     // col (16-elem segment)
    const float* src = (kk < Isz) ? (x + (size_t)b * Isz + kk)
                                  : (h + (size_t)b * Hsz + (kk - Isz));
    const float4 v0 = ((const float4*)src)[0];
    const float4 v1 = ((const float4*)src)[1];
    const float4 v2 = ((const float4*)src)[2];
    const float4 v3 = ((const float4*)src)[3];
    __hip_bfloat16* dst = Abf + (size_t)b * Ksz + kk;
    ((ushort8*)dst)[0] = cvt8v(v0, v1);
    ((ushort8*)dst)[1] = cvt8v(v2, v3);
  }

  // W': 4096 permuted rows x 128 segments = 524,288 segs; 1 per thread
  {
    const int r = idx >> 7;            // permuted row 4*hh+g
    const int kk = (idx & 127) << 4;
    const int hh = r >> 2, g = r & 3;
    const float* src = (kk < Isz)
        ? (Wx + (size_t)(g * Hsz + hh) * Isz + kk)
        : (Wh + (size_t)(g * Hsz + hh) * Hsz + (kk - Isz));
    const float4 v0 = ((const float4*)src)[0];
    const float4 v1 = ((const float4*)src)[1];
    const float4 v2 = ((const float4*)src)[2];
    const float4 v3 = ((const float4*)src)[3];
    __hip_bfloat16* dst = Wbf + (size_t)r * Ksz + kk;
    ((ushort8*)dst)[0] = cvt8v(v0, v1);
    ((ushort8*)dst)[1] = cvt8v(v2, v3);
  }

  if (idx < Nsz) {
    const int hh = idx >> 2, g = idx & 3;
    bsum[idx] = bx[g * Hsz + hh] + bh[g * Hsz + hh];
  }
}

// ---------------------------------------------------------------------------
// GEMM (A·W'^T) + fused LSTM epilogue — ROUND-3 KERNEL RESTORED VERBATIM
// (best measured: 134.4-135.4 us). Round-4's read-ahead variant regressed to
// 138.5-140.3 and is reverted. This dispatch is the CONTROL for the prep
// experiment: expected dur 134-136, MfmaUtil ~43.5, VGPR 104.
//
// Structure: 256² tile, B triple-buffered (160 KB LDS), ONE barrier per
// K-tile, 8-MFMA clusters split by K-half, reads just-in-time, counted
// vmcnt(4) (never 0 mid-loop). Hazard proofs in round-3 notes.
// ---------------------------------------------------------------------------
__global__ __launch_bounds__(512, 2) void lstm_gemm_kernel(
    const __hip_bfloat16* __restrict__ A,   // [8192][2048]
    const __hip_bfloat16* __restrict__ W,   // [4096][2048] gate-interleaved
    const float* __restrict__ bsum,         // [4096] gate-interleaved
    const float* __restrict__ c_prev,       // [8192][1024]
    float* __restrict__ c_out,              // [8192][1024]
    float* __restrict__ h_out) {            // [8192][1024]
  __shared__ ulong2 smem_raw[10240];        // 160 KB exactly
  __hip_bfloat16* const As = (__hip_bfloat16*)smem_raw;   // 2 bufs @ 0, 32 KB
  __hip_bfloat16* const Bs = As + 2 * BUF;                // 3 bufs @ 64 KB+

  const int tid = threadIdx.x;
  const int lane = tid & 63;
  const int wave = tid >> 6;     // 0..7
  const int wm = wave >> 2;      // 0..1 : 128-row half of the 256-row tile
  const int wn = wave & 3;       // 0..3 : 64-col strip of the 256-col tile

  // T1: bijective XCD swizzle (512 blocks, 512 % 8 == 0).
  const int orig = blockIdx.x;
  const int swz = (orig & 7) * 64 + (orig >> 3);
  const int bx = swz & 31;       // 32 row tiles
  const int by = swz >> 5;       // 16 col tiles
  const int row0 = bx * BM;
  const int col0 = by * BN;

  const __hip_bfloat16* const Ag = A + (size_t)row0 * Ksz;
  const __hip_bfloat16* const Wg = W + (size_t)col0 * Ksz;

  // staging: half-tile = 128 rows x 64 cols = 1024 x 16 B chunks; thread
  // stages chunks tid and tid+512 (rows sr, sr+64; 64%8==0 -> same swizzle).
  const int sr = tid >> 3;                       // 0..63
  const int so = ((tid & 7) ^ (sr & 7)) << 3;    // pre-swizzled elem offset

  auto stage = [&](const __hip_bfloat16* gsrc, char* lhalf) {
#pragma unroll
    for (int p = 0; p < 2; ++p)
      async_copy16(gsrc + (size_t)(sr + p * 64) * Ksz,
                   lhalf + (tid + p * 512) * 16);
  };

  const int q = lane >> 4;    // quad
  const int cl = lane & 15;   // row-in-16 within a fragment
  const int phi = cl & 7;     // read-side swizzle phase
  const int swz0 = ((0 + q) ^ phi) << 3;   // ks=0 qword slot -> elem offset
  const int swz1 = ((4 + q) ^ phi) << 3;   // ks=1
  const int aoff0 = (wm * 128 + cl) * BK + swz0;
  const int aoff1 = (wm * 128 + cl) * BK + swz1;
  const int boff0 = (wn * 64 + cl) * BK + swz0;
  const int boff1 = (wn * 64 + cl) * BK + swz1;

  // rotating B buffer pointers: read Bp0 (t%3), write Bp2 ((t+2)%3)
  const __hip_bfloat16* Bp0 = Bs;
  const __hip_bfloat16* Bp1 = Bs + BUF;
  const __hip_bfloat16* Bp2 = Bs + 2 * BUF;

  // ---- prologue: A(0) -> Abuf0; B(0) -> Bbuf0; B(1) -> Bbuf1 (B(1) may fly)
  stage(Ag + so, (char*)As);
  stage(Ag + (size_t)128 * Ksz + so, (char*)As + 16384);
  stage(Wg + so, (char*)Bs);
  stage(Wg + (size_t)128 * Ksz + so, (char*)Bs + 16384);
  __builtin_amdgcn_sched_barrier(0);   // pin VMEM order for vmcnt counting
  stage(Wg + BK + so, (char*)(Bs + BUF));
  stage(Wg + BK + (size_t)128 * Ksz + so, (char*)(Bs + BUF) + 16384);
  __builtin_amdgcn_sched_barrier(0);
  asm volatile("s_waitcnt vmcnt(4)" ::: "memory");  // A(0),B(0) landed
  __builtin_amdgcn_s_barrier();
  __builtin_amdgcn_sched_barrier(0);

  f32x4 acc[8][4] = {};

#define SB0 __builtin_amdgcn_sched_barrier(0);

// read A fragment pair (rows m, m+1), one K-half ks, into dst[0..1][ks]
#define LDA2(dst, m, ks)                                                   \
  dst[0][ks] = *(const bf16x8*)(Asb + aoff##ks + (m) * (16 * BK));         \
  dst[1][ks] = *(const bf16x8*)(Asb + aoff##ks + ((m) + 1) * (16 * BK));

// read all 4 B fragments of one K-half
#define LDB(ks)                                                            \
  _Pragma("unroll")                                                        \
  for (int n = 0; n < 4; ++n)                                              \
    b[n][ks] = *(const bf16x8*)(Bsb + boff##ks + n * (16 * BK));

// 8-MFMA cluster: rows mi,mi+1 x 4n x one K-half, setprio-wrapped
#define CL(mi, ks, p)                                                      \
  __builtin_amdgcn_s_setprio(1);                                           \
  _Pragma("unroll")                                                        \
  for (int n = 0; n < 4; ++n) {                                            \
    acc[mi][n] = __builtin_amdgcn_mfma_f32_16x16x32_bf16(                  \
        p[0][ks], b[n][ks], acc[mi][n], 0, 0, 0);                          \
    acc[(mi) + 1][n] = __builtin_amdgcn_mfma_f32_16x16x32_bf16(            \
        p[1][ks], b[n][ks], acc[(mi) + 1][n], 0, 0, 0);                    \
  }                                                                        \
  __builtin_amdgcn_s_setprio(0);                                           \
  __builtin_amdgcn_sched_barrier(0);

  for (int t = 0; t < NT; ++t) {
    const __hip_bfloat16* const Asb = As + (t & 1) * BUF;
    const __hip_bfloat16* const Bsb = Bp0;
    char* const nA = (char*)As + ((t + 1) & 1) * 32768;   // (t+1).A dest
    char* const nB = (char*)Bp2;                          // (t+2).B dest
    const int kA = (t + 1) * BK;
    const int kB = (t + 2) * BK;
    const bool doA = (t + 1) < NT;   // uniform
    const bool doB = (t + 2) < NT;   // uniform

    bf16x8 b[4][2];              // B fragments, both K-halves
    bf16x8 aE[2][2], aO[2][2];   // ping-pong A fragment pairs

    // R0 (exposed once per tile): 6 reads gate the first cluster
    LDB(0) LDA2(aE, 0, 0)
    if (doA) stage(Ag + kA + so, nA);
    SB0
    CL(0, 0, aE)

    LDB(1) LDA2(aE, 0, 1)
    if (doA) stage(Ag + kA + (size_t)128 * Ksz + so, nA + 16384);
    SB0
    CL(0, 1, aE)

    LDA2(aO, 2, 0)
    if (doB) stage(Wg + kB + so, nB);
    SB0
    CL(2, 0, aO)

    LDA2(aO, 2, 1)
    if (doB) stage(Wg + kB + (size_t)128 * Ksz + so, nB + 16384);
    SB0
    CL(2, 1, aO)

    LDA2(aE, 4, 0) SB0 CL(4, 0, aE)
    LDA2(aE, 4, 1) SB0 CL(4, 1, aE)
    LDA2(aO, 6, 0) SB0 CL(6, 0, aO)
    LDA2(aO, 6, 1) SB0 CL(6, 1, aO)

    // end-of-tile: counted drain; B(t+2) stays flying across the barrier
    if (t < NT - 2) {
      asm volatile("s_waitcnt vmcnt(4)" ::: "memory");
    } else if (t == NT - 2) {
      asm volatile("s_waitcnt vmcnt(0)" ::: "memory");   // drain for tail
    }
    __builtin_amdgcn_s_barrier();
    __builtin_amdgcn_sched_barrier(0);

    // rotate B buffers: new read = old Bp1; new write = old Bp0
    const __hip_bfloat16* const tmp = Bp0;
    Bp0 = Bp1; Bp1 = Bp2; Bp2 = tmp;
  }
#undef LDA2
#undef LDB
#undef CL
#undef SB0

  // ---- fused LSTM epilogue (LDS round-trip in the now-dead buffer space) ----
  __syncthreads();
  float* const E = (float*)smem_raw + wave * (16 * 68);   // 8 x 4352 B = 34 KB

  float bj[4];
#pragma unroll
  for (int n = 0; n < 4; ++n)
    bj[n] = bsum[col0 + wn * 64 + n * 16 + cl];

  const int hw = (col0 >> 2) + wn * 16;  // wave's h-window start (16 h values)
  const int r16 = lane >> 2;             // read-phase row 0..15
  const int tt = lane & 3;               // read-phase h-quad 0..3

#pragma unroll
  for (int i = 0; i < 8; ++i) {
    // write phase: lane (q,cl) reg r holds C[q*4+r][n*16+cl] of this 16-row tile
#pragma unroll
    for (int n = 0; n < 4; ++n)
#pragma unroll
      for (int r = 0; r < 4; ++r)
        E[(q * 4 + r) * 68 + n * 16 + cl] = acc[i][n][r] + bj[n];
    __builtin_amdgcn_wave_barrier();  // keep write->read order (wave-private)
    // read phase: lane owns row r16, h = hw + tt*4 + (0..3); gate cols 4h'+g
    const float* Er = E + r16 * 68 + tt * 16;
    const float4 f0 = ((const float4*)Er)[0];  // gates of h+0
    const float4 f1 = ((const float4*)Er)[1];  // gates of h+1
    const float4 f2 = ((const float4*)Er)[2];  // gates of h+2
    const float4 f3 = ((const float4*)Er)[3];  // gates of h+3

    const int row = row0 + wm * 128 + i * 16 + r16;
    const size_t off = (size_t)row * Hsz + hw + tt * 4;
    const float4 cp4 = *(const float4*)(c_prev + off);
    float4 c4, h4;
    {
      const float cn = sigmoid_f(f0.y) * cp4.x + sigmoid_f(f0.x) * tanh_f(f0.w);
      c4.x = cn; h4.x = sigmoid_f(f0.z) * tanh_f(cn);
    }
    {
      const float cn = sigmoid_f(f1.y) * cp4.y + sigmoid_f(f1.x) * tanh_f(f1.w);
      c4.y = cn; h4.y = sigmoid_f(f1.z) * tanh_f(cn);
    }
    {
      const float cn = sigmoid_f(f2.y) * cp4.z + sigmoid_f(f2.x) * tanh_f(f2.w);
      c4.z = cn; h4.z = sigmoid_f(f2.z) * tanh_f(cn);
    }
    {
      const float cn = sigmoid_f(f3.y) * cp4.w + sigmoid_f(f3.x) * tanh_f(f3.w);
      c4.w = cn; h4.w = sigmoid_f(f3.z) * tanh_f(cn);
    }
    *(float4*)(c_out + off) = c4;
    *(float4*)(h_out + off) = h4;
    __builtin_amdgcn_wave_barrier();  // next i reuses E
  }
}

extern "C" void kernel_launch(void* const* d_in, const int* in_sizes, int n_in,
                              void* d_out, int out_size, void* d_ws,
                              size_t ws_size, hipStream_t stream) {
  (void)in_sizes; (void)n_in; (void)out_size; (void)ws_size;
  const float* x  = (const float*)d_in[0];
  const float* cp = (const float*)d_in[1];
  const float* hp = (const float*)d_in[2];
  const float* Wx = (const float*)d_in[3];
  const float* bx = (const float*)d_in[4];
  const float* Wh = (const float*)d_in[5];
  const float* bh = (const float*)d_in[6];

  __hip_bfloat16* Abf = (__hip_bfloat16*)d_ws;            // 32 MB
  __hip_bfloat16* Wbf = Abf + (size_t)Bsz * Ksz;          // 16 MB
  float* bsum = (float*)(Wbf + (size_t)Nsz * Ksz);        // 16 KB

  float* c_out = (float*)d_out;
  float* h_out = c_out + (size_t)Bsz * Hsz;

  // 524,288 threads, 3 fat segments each (2x A + 1x W), grid-strided layout
  prep_kernel<<<2048, 256, 0, stream>>>(x, hp, Wx, Wh, bx, bh,
                                        Abf, Wbf, bsum);
  dim3 grid(Bsz / BM * (Nsz / BN));  // 32 x 16 = 512 blocks (1D, swizzled)
  lstm_gemm_kernel<<<grid, 512, 0, stream>>>(Abf, Wbf, bsum, cp, c_out, h_out);
}